// Round 7
// baseline (327.129 us; speedup 1.0000x reference)
//
#include <hip/hip_runtime.h>
#include <stdint.h>

#define B_  16
#define C_  512
#define S_  1024
#define NSAMP (C_*S_)

typedef __bf16 bf16x8 __attribute__((ext_vector_type(8)));
typedef float  f32x4  __attribute__((ext_vector_type(4)));

__device__ __forceinline__ float bf2f(uint16_t u){ return __uint_as_float(((uint32_t)u)<<16); }
__device__ __forceinline__ uint16_t f2bf(float f){
  uint32_t u = __float_as_uint(f);
  uint32_t r = u + 0x7fffu + ((u>>16)&1u);   // RNE
  return (uint16_t)(r>>16);
}
__device__ __forceinline__ float wsum(float v){
  #pragma unroll
  for(int o=32;o;o>>=1) v += __shfl_xor(v,o,64);
  return v;
}
__device__ __forceinline__ int wsumi(int v){
  #pragma unroll
  for(int o=32;o;o>>=1) v += __shfl_xor(v,o,64);
  return v;
}
__device__ __forceinline__ void gload16(const void* g, void* l){
  __builtin_amdgcn_global_load_lds(
      (__attribute__((address_space(1))) void*)g,
      (__attribute__((address_space(3))) void*)l, 16, 0, 0);
}

// ---------- merged prep: x->bf16 + GN partials (blocks 0..1023) | params->bf16 (1024..1536) ----------
__device__ __forceinline__ void convseg(const void* src, uint16_t* dst, int n, int f, int t){
  const int idx = t*8;
  if (idx >= n) return;
  if (f){
    const float* s = (const float*)src;
    float4 v0 = *(const float4*)(s + idx);
    float4 v1 = *(const float4*)(s + idx + 4);
    ushort4 a, b;
    a.x=f2bf(v0.x); a.y=f2bf(v0.y); a.z=f2bf(v0.z); a.w=f2bf(v0.w);
    b.x=f2bf(v1.x); b.y=f2bf(v1.y); b.z=f2bf(v1.z); b.w=f2bf(v1.w);
    *(ushort4*)(dst + idx)     = a;
    *(ushort4*)(dst + idx + 4) = b;
  } else {
    *(uint4*)(dst + idx) = *(const uint4*)((const uint16_t*)src + idx);
  }
}
__global__ __launch_bounds__(256) void prep_k(
    const void* __restrict__ srcx, uint16_t* __restrict__ xb, float2* __restrict__ part,
    const void* qkvw, const void* projw, const void* gnw, const void* gnb,
    const void* qkvb, const void* projb,
    uint16_t* qkvwb, uint16_t* projwb, uint16_t* gnwb, uint16_t* gnbb,
    uint16_t* qkvbb, uint16_t* projbb, int* __restrict__ flag){
  const int t = threadIdx.x;
  __shared__ int sdet[4];
  int f;
  {
    const uint4 v = ((const uint4*)srcx)[t & 255];
    uint32_t ww[4] = {v.x, v.y, v.z, v.w};
    int c = 0;
    #pragma unroll
    for(int q=0;q<4;q++) c += ((((ww[q] & 0xffffu) >> 7) & 0xffu) >= 132) ? 1 : 0;
    c = wsumi(c);
    if ((t & 63) == 0) sdet[t >> 6] = c;
    __syncthreads();
    f = (sdet[0] + sdet[1] + sdet[2] + sdet[3] > 128) ? 1 : 0;   // 1 => fp32
  }
  if (blockIdx.x == 0 && t == 0) *flag = f;

  if (blockIdx.x >= 1024){
    const int bid = blockIdx.x - 1024;
    if (bid < 384){
      const size_t off = (size_t)bid*2048;
      convseg((const char*)qkvw + off*(f?4:2), qkvwb + off, 2048, f, t);
    } else if (bid < 512){
      const size_t off = (size_t)(bid-384)*2048;
      convseg((const char*)projw + off*(f?4:2), projwb + off, 2048, f, t);
    } else {
      convseg(gnw,   gnwb,   512,  f, t);
      convseg(gnb,   gnbb,   512,  f, t);
      convseg(qkvb,  qkvbb,  1536, f, t);
      convseg(projb, projbb, 512,  f, t);
    }
    return;
  }
  const size_t base = (size_t)blockIdx.x * 8192;
  float s = 0.f, s2 = 0.f;
  if (f){
    const float4* sp = (const float4*)((const float*)srcx + base);
    ushort4* dp = (ushort4*)(xb + base);
    #pragma unroll
    for(int i=0;i<8;i++){
      float4 v = sp[i*256 + t];
      s  += v.x + v.y + v.z + v.w;
      s2 += v.x*v.x + v.y*v.y + v.z*v.z + v.w*v.w;
      ushort4 o; o.x=f2bf(v.x); o.y=f2bf(v.y); o.z=f2bf(v.z); o.w=f2bf(v.w);
      dp[i*256 + t] = o;
    }
  } else {
    const uint4* sp = (const uint4*)((const uint16_t*)srcx + base);
    uint4* dp = (uint4*)(xb + base);
    #pragma unroll
    for(int i=0;i<4;i++){
      uint4 p = sp[i*256 + t];
      dp[i*256 + t] = p;
      uint32_t uu[4] = {p.x,p.y,p.z,p.w};
      #pragma unroll
      for(int q=0;q<4;q++){
        float f0 = __uint_as_float(uu[q]<<16);
        float f1 = __uint_as_float(uu[q] & 0xffff0000u);
        s += f0 + f1; s2 += f0*f0 + f1*f1;
      }
    }
  }
  s = wsum(s); s2 = wsum(s2);
  __shared__ float rs[4], rq[4];
  const int lane = t & 63, w = t >> 6;
  if (lane==0){ rs[w]=s; rq[w]=s2; }
  __syncthreads();
  if (t==0)
    part[blockIdx.x] = make_float2(rs[0]+rs[1]+rs[2]+rs[3], rq[0]+rq[1]+rq[2]+rq[3]);
}

// ---- GN apply + transpose [B,C,S] -> hT [B,S,C] bf16 ----
__global__ __launch_bounds__(256) void gn_apply_t(const uint16_t* __restrict__ x,
    const uint16_t* __restrict__ gw, const uint16_t* __restrict__ gb,
    const float2* __restrict__ part, uint16_t* __restrict__ hT){
  __shared__ float tile[64*129];
  const int b = blockIdx.z, c0 = blockIdx.y<<6, s0 = blockIdx.x<<7;
  const int t = threadIdx.x;
  float2 p = part[b*64 + (t & 63)];
  float s = wsum(p.x), s2 = wsum(p.y);
  const float ninv = 1.f/(float)NSAMP;
  const float mn = s*ninv;
  const float rstd = rsqrtf(s2*ninv - mn*mn + 1e-5f);
  #pragma unroll
  for(int k=0;k<4;k++){
    const int ci = t + k*256;
    const int cl = ci>>4, sc = ci&15;
    uint4 v = *(const uint4*)&x[((size_t)b*C_ + c0+cl)*S_ + s0 + sc*8];
    const uint16_t* e = (const uint16_t*)&v;
    float* dst = &tile[cl*129 + sc*8];
    #pragma unroll
    for(int q=0;q<8;q++) dst[q] = bf2f(e[q]);
  }
  __syncthreads();
  const int cc = t & 7;
  const int sb0 = t >> 3;
  uint4 wv4 = *(const uint4*)&gw[c0 + cc*8];
  uint4 bv4 = *(const uint4*)&gb[c0 + cc*8];
  const uint16_t* we = (const uint16_t*)&wv4;
  const uint16_t* be = (const uint16_t*)&bv4;
  float aq[8], cq[8];
  #pragma unroll
  for(int q=0;q<8;q++){ aq[q] = bf2f(we[q])*rstd; cq[q] = bf2f(be[q]) - mn*aq[q]; }
  #pragma unroll
  for(int k=0;k<4;k++){
    const int sl = sb0 + k*32;
    uint16_t ov[8];
    #pragma unroll
    for(int q=0;q<8;q++){
      float xv = tile[(cc*8+q)*129 + sl];
      ov[q] = f2bf(xv*aq[q] + cq[q]);
    }
    uint4 o;
    o.x = (uint32_t)ov[0] | ((uint32_t)ov[1]<<16);
    o.y = (uint32_t)ov[2] | ((uint32_t)ov[3]<<16);
    o.z = (uint32_t)ov[4] | ((uint32_t)ov[5]<<16);
    o.w = (uint32_t)ov[6] | ((uint32_t)ov[7]<<16);
    *(uint4*)&hT[((size_t)b*S_ + s0+sl)*C_ + c0 + cc*8] = o;
  }
}

// ======== merged QK + V^T GEMMs (dbuf + counted vmcnt) ========
__global__ __launch_bounds__(256)
void qkv_k(const uint16_t* __restrict__ hT, const uint16_t* __restrict__ qkvw,
           const uint16_t* __restrict__ qkvb, uint16_t* __restrict__ qk,
           uint16_t* __restrict__ Vt)
{
  __shared__ uint16_t smem[32768];
  const int tid = threadIdx.x;
  const int lane = tid & 63, w = tid >> 6;
  const int quad = lane >> 4, lm = lane & 15;
  const int wm = (w & 1) << 6, wn = (w >> 1) << 6;

  const bool vpath = blockIdx.x >= 1024;
  const int id = vpath ? (blockIdx.x - 1024) : blockIdx.x;
  const int r8 = id & 7, k8 = id >> 3;
  int m0, n0, bz;
  const uint16_t *Abase, *Bbase;
  if (!vpath){
    const int g = r8*16 + (k8 & 15);
    m0 = g << 7; n0 = (k8 >> 4) << 7; bz = 0;
    Abase = hT + (size_t)m0*512;
    Bbase = qkvw + (size_t)n0*512;
  } else {
    const int g = r8*16 + (k8 & 15);
    m0 = (k8 >> 4) << 7; n0 = (g & 7) << 7; bz = g >> 3;
    Abase = qkvw + (size_t)(1024 + m0)*512;
    Bbase = hT + (size_t)bz*S_*C_ + (size_t)n0*512;
  }

  f32x4 acc[4][4];
  #pragma unroll
  for(int i=0;i<4;i++)
    #pragma unroll
    for(int j=0;j<4;j++) acc[i][j] = (f32x4){0.f,0.f,0.f,0.f};

  const int srow = tid >> 3;
  const int sx   = (tid & 7) ^ (srow & 7);
  const uint16_t* ga = Abase + (size_t)srow*512 + sx*8;
  const uint16_t* gb = Bbase + (size_t)srow*512 + sx*8;
  uint16_t* sa0 = &smem[tid*8];
  uint16_t* sb0 = &smem[8192 + tid*8];
  uint16_t* sa1 = &smem[16384 + tid*8];
  uint16_t* sb1 = &smem[24576 + tid*8];

  #pragma unroll
  for(int i=0;i<4;i++){
    gload16(ga + (size_t)(i*32)*512, sa0 + i*2048);
    gload16(gb + (size_t)(i*32)*512, sb0 + i*2048);
  }
  for(int t=0;t<8;t++){
    if (t < 7){
      uint16_t* na = (t&1) ? sa0 : sa1;
      uint16_t* nb = (t&1) ? sb0 : sb1;
      const int k1 = (t+1)<<6;
      #pragma unroll
      for(int i=0;i<4;i++){
        gload16(ga + (size_t)(i*32)*512 + k1, na + i*2048);
        gload16(gb + (size_t)(i*32)*512 + k1, nb + i*2048);
      }
      asm volatile("s_waitcnt vmcnt(8)" ::: "memory");
    } else {
      asm volatile("s_waitcnt vmcnt(0)" ::: "memory");
    }
    __builtin_amdgcn_s_barrier();
    __builtin_amdgcn_sched_barrier(0);
    const int boff = (t&1) << 14;
    #pragma unroll
    for(int kk=0;kk<64;kk+=32){
      bf16x8 av[4], bv[4];
      #pragma unroll
      for(int i=0;i<4;i++){
        const int row = wm + i*16 + lm;
        av[i] = *(const bf16x8*)&smem[boff + row*64 + ((((kk>>3)+quad) ^ (row&7))<<3)];
      }
      #pragma unroll
      for(int j=0;j<4;j++){
        const int row = wn + j*16 + lm;
        bv[j] = *(const bf16x8*)&smem[boff + 8192 + row*64 + ((((kk>>3)+quad) ^ (row&7))<<3)];
      }
      #pragma unroll
      for(int i=0;i<4;i++)
        #pragma unroll
        for(int j=0;j<4;j++)
          acc[i][j] = __builtin_amdgcn_mfma_f32_16x16x32_bf16(av[i], bv[j], acc[i][j], 0,0,0);
    }
    __builtin_amdgcn_s_barrier();
  }

  uint16_t* Cs = smem;
  if (!vpath){
    #pragma unroll
    for(int j=0;j<4;j++){
      const int col_l = wn + j*16 + lm;
      const float bvv = bf2f(qkvb[n0 + col_l]);
      #pragma unroll
      for(int i=0;i<4;i++){
        const int rl0 = wm + i*16 + (quad<<2);
        #pragma unroll
        for(int r=0;r<4;r++)
          Cs[(rl0+r)*128 + col_l] = f2bf(acc[i][j][r] + bvv);
      }
    }
  } else {
    #pragma unroll
    for(int i=0;i<4;i++){
      const int rl0 = wm + i*16 + (quad<<2);
      #pragma unroll
      for(int r=0;r<4;r++){
        const float bvv = bf2f(qkvb[1024 + m0 + rl0 + r]);
        #pragma unroll
        for(int j=0;j<4;j++)
          Cs[(rl0+r)*128 + wn + j*16 + lm] = f2bf(acc[i][j][r] + bvv);
      }
    }
  }
  __syncthreads();
  uint16_t* base = vpath ? (Vt + (size_t)bz*C_*S_) : qk;
  #pragma unroll
  for(int k=0;k<8;k++){
    const int ci = tid + k*256;
    const int rl = ci>>4, ccc = ci&15;
    *(uint4*)&base[(size_t)(m0+rl)*1024 + n0 + ccc*8] = *(const uint4*)&Cs[rl*128 + ccc*8];
  }
}

// ============ fused flash attention v2: wave-specialized producer/consumer ============
// 256 blocks x 1024 threads (16 waves). Waves 0-7: QK^T+exp -> P (LDS, dbuf).
// Waves 8-15: PV with private V staging. All staging wave-private (vmcnt-only sync);
// ONE workgroup barrier per kt phase. Q direct from global (L2-hot re-reads).
// LDS 160KB: KST 64K (8 prod waves x ring2 x 4K) | VST 64K (8 cons waves x ring2 x 4K)
//            | Pb 32K (2 x [64][128] swz). RS reuses Pb[0] at t=8; Cs reuses KST.
__global__ __launch_bounds__(1024, 4)
void fa_k(const uint16_t* __restrict__ qk, const uint16_t* __restrict__ Vt,
          uint16_t* __restrict__ out)
{
  extern __shared__ char smem[];
  char* KST = smem;
  char* VST = smem + 65536;
  char* Pb  = smem + 131072;
  float* RS = (float*)Pb;              // Pb[0] dead after t=7 consumption

  const int tid = threadIdx.x;
  const int w = tid >> 6, lane = tid & 63;
  const int quad = lane >> 4, lm = lane & 15;

  const int wg = (blockIdx.x & 7)*32 + (blockIdx.x >> 3);   // batch-per-XCD
  const int bz = wg >> 4;
  const int q0 = (wg & 15) << 6;

  const bool isQKT = (w < 8);
  const int wq = w & 1, wk = (w >> 1) & 3;   // producer grid 2q x 4k
  const int pw = w & 7;                       // consumer ch-block

  const uint16_t* kbase = qk + (size_t)bz*1024*1024 + 512;
  const uint16_t* qrow0 = qk + ((size_t)bz*1024 + q0 + wq*32 + lm)*1024 + quad*8;
  const uint16_t* qrow1 = qrow0 + (size_t)16*1024;
  const uint16_t* vbase = Vt + ((size_t)bz*512 + pw*64)*1024;

  char* kpriv = KST + w*8192;
  char* vpriv = VST + pw*8192;

  f32x4 o[4][4];
  #pragma unroll
  for(int i=0;i<4;i++)
    #pragma unroll
    for(int j=0;j<4;j++) o[i][j] = (f32x4){0.f,0.f,0.f,0.f};
  float rsacc[2][4];
  #pragma unroll
  for(int i=0;i<2;i++)
    #pragma unroll
    for(int r=0;r<4;r++) rsacc[i][r] = 0.f;

  auto stage_kp = [&](int kt, int ch){
    char* dst = kpriv + ((ch&1)<<12);
    #pragma unroll
    for (int g=0; g<4; ++g){
      const int idx = g*64 + lane;
      const int row = idx >> 3, c8 = idx & 7;
      gload16(kbase + (size_t)(kt*128 + wk*32 + row)*1024 + ch*64 + ((c8 ^ (row&7))<<3),
              dst + idx*16);
    }
  };
  auto stage_vp = [&](int kt, int kk){
    char* dst = vpriv + ((kk&1)<<12);
    #pragma unroll
    for (int g=0; g<4; ++g){
      const int idx = g*64 + lane;
      const int c = idx >> 2, c4 = idx & 3;
      gload16(vbase + (size_t)c*1024 + kt*128 + kk*32 + ((c4 ^ (c&3))<<3),
              dst + idx*16);
    }
  };

  if (isQKT) stage_kp(0, 0);

  for (int t=0; t<9; ++t){
    __builtin_amdgcn_s_barrier();
    if (isQKT){
      if (t < 8){
        f32x4 s[2][2];
        #pragma unroll
        for(int i=0;i<2;i++)
          #pragma unroll
          for(int j=0;j<2;j++) s[i][j] = (f32x4){0.f,0.f,0.f,0.f};
        char* Pw = Pb + ((t&1)<<14);
        #pragma unroll
        for (int ch=0; ch<8; ++ch){
          if (ch < 7)      stage_kp(t, ch+1);
          else if (t < 7)  stage_kp(t+1, 0);
          asm volatile("s_waitcnt vmcnt(4)" ::: "memory");
          __builtin_amdgcn_sched_barrier(0);
          const bf16x8 a00 = *(const bf16x8*)(qrow0 + ch*64);
          const bf16x8 a10 = *(const bf16x8*)(qrow1 + ch*64);
          const bf16x8 a01 = *(const bf16x8*)(qrow0 + ch*64 + 32);
          const bf16x8 a11 = *(const bf16x8*)(qrow1 + ch*64 + 32);
          const char* kslot = kpriv + ((ch&1)<<12);
          #pragma unroll
          for (int kk=0; kk<2; ++kk){
            const int sw = (((kk<<2)+quad) ^ (lm&7)) << 4;
            bf16x8 bv0 = *(const bf16x8*)(kslot + lm*128 + sw);
            bf16x8 bv1 = *(const bf16x8*)(kslot + (16+lm)*128 + sw);
            const bf16x8 A0 = kk ? a01 : a00;
            const bf16x8 A1 = kk ? a11 : a10;
            s[0][0] = __builtin_amdgcn_mfma_f32_16x16x32_bf16(A0, bv0, s[0][0], 0,0,0);
            s[0][1] = __builtin_amdgcn_mfma_f32_16x16x32_bf16(A0, bv1, s[0][1], 0,0,0);
            s[1][0] = __builtin_amdgcn_mfma_f32_16x16x32_bf16(A1, bv0, s[1][0], 0,0,0);
            s[1][1] = __builtin_amdgcn_mfma_f32_16x16x32_bf16(A1, bv1, s[1][1], 0,0,0);
          }
        }
        // exp + P write + rowsum accumulate
        #pragma unroll
        for (int i=0;i<2;i++)
          #pragma unroll
          for (int j=0;j<2;j++)
            #pragma unroll
            for (int r=0;r<4;r++){
              const int q = wq*32 + i*16 + (quad<<2) + r;
              const int col = wk*32 + j*16 + lm;
              const float pv = __expf(s[i][j][r] * 0.044194173824159216f);
              rsacc[i][r] += pv;
              const int cch = col >> 3;
              const int chs = (cch & 8) | ((cch & 7) ^ (q & 7));
              *(uint16_t*)(Pw + q*256 + chs*16 + ((col & 7)<<1)) = f2bf(pv);
            }
        asm volatile("s_waitcnt lgkmcnt(0)" ::: "memory");
      } else {
        // t==8: publish rowsums (lm-reduce within quad group, then per-wk partial)
        #pragma unroll
        for (int i=0;i<2;i++)
          #pragma unroll
          for (int r=0;r<4;r++){
            float v = rsacc[i][r];
            #pragma unroll
            for (int off=1; off<16; off<<=1) v += __shfl_xor(v, off, 64);
            rsacc[i][r] = v;
          }
        if (lm == 0){
          #pragma unroll
          for (int i=0;i<2;i++)
            #pragma unroll
            for (int r=0;r<4;r++){
              const int q = wq*32 + i*16 + (quad<<2) + r;
              RS[q*4 + wk] = rsacc[i][r];
            }
        }
        asm volatile("s_waitcnt lgkmcnt(0)" ::: "memory");
      }
    } else {
      if (t > 0){
        const int kt = t-1;
        const char* Pr = Pb + ((kt&1)<<14);
        stage_vp(kt, 0);
        stage_vp(kt, 1);
        #pragma unroll
        for (int kk=0; kk<4; ++kk){
          if (kk < 3) asm volatile("s_waitcnt vmcnt(4)" ::: "memory");
          else        asm volatile("s_waitcnt vmcnt(0)" ::: "memory");
          __builtin_amdgcn_sched_barrier(0);
          bf16x8 pa[4], bv[4];
          #pragma unroll
          for (int i=0;i<4;i++){
            const int q = i*16 + lm;
            const int cch = (kk<<2) + quad;
            const int chs = (cch & 8) | ((cch & 7) ^ (q & 7));
            pa[i] = *(const bf16x8*)(Pr + q*256 + chs*16);
          }
          #pragma unroll
          for (int j=0;j<4;j++){
            const int c = j*16 + lm;
            bv[j] = *(const bf16x8*)(vpriv + ((kk&1)<<12) + c*64 + ((quad ^ (c&3))<<4));
          }
          #pragma unroll
          for (int i=0;i<4;i++)
            #pragma unroll
            for (int j=0;j<4;j++)
              o[i][j] = __builtin_amdgcn_mfma_f32_16x16x32_bf16(pa[i], bv[j], o[i][j], 0,0,0);
          __builtin_amdgcn_sched_barrier(0);
          if (kk < 2) stage_vp(kt, kk+2);
        }
      }
    }
  }

  // ---- epilogue ----
  __builtin_amdgcn_s_barrier();          // RS visible; PV MFMAs done
  uint16_t* Cs = (uint16_t*)smem;        // KST region (dead)
  if (!isQKT){
    float inv_[4][4];
    #pragma unroll
    for (int i=0;i<4;i++)
      #pragma unroll
      for (int r=0;r<4;r++){
        const int q = i*16 + (quad<<2) + r;
        f32x4 rv = *(const f32x4*)&RS[q*4];
        inv_[i][r] = 1.f / (rv[0]+rv[1]+rv[2]+rv[3]);
      }
    #pragma unroll
    for (int i=0;i<4;i++)
      #pragma unroll
      for (int j=0;j<4;j++)
        #pragma unroll
        for (int r=0;r<4;r++){
          const int row = i*16 + (quad<<2) + r;
          const int col = pw*64 + j*16 + lm;
          Cs[row*512 + col] = f2bf(o[i][j][r] * inv_[i][r]);
        }
  }
  asm volatile("s_waitcnt lgkmcnt(0)" ::: "memory");
  __builtin_amdgcn_s_barrier();
  #pragma unroll
  for (int rd=0; rd<4; ++rd){
    const int idx = rd*1024 + tid;
    const int row = idx >> 6, cc = idx & 63;
    *(uint4*)&out[((size_t)bz*1024 + q0 + row)*512 + cc*8] =
        *(const uint4*)((const char*)Cs + row*1024 + cc*16);
  }
}

// ---------------- 128x128 MFMA GEMM (proj only now) ----------------
template<bool HASBIAS, bool BIASROW, bool OUTDYN, bool HASRES, int SWZMODE, bool EXP>
__global__ __launch_bounds__(256)
void gemm_bt(const uint16_t* __restrict__ A, const uint16_t* __restrict__ Bt,
             void* __restrict__ Cp, const uint16_t* __restrict__ bias,
             const uint16_t* __restrict__ xres, const int* __restrict__ flag,
             int lda, int ldb, int ldc, int K,
             long long sA, long long sB, long long sC)
{
  __shared__ uint16_t smem[32768];
  const int lin = (blockIdx.z * gridDim.y + blockIdx.y) * gridDim.x + blockIdx.x;
  const int r8 = lin & 7, kk8 = lin >> 3;
  int bx, by, bz;
  if (SWZMODE == 0){
    const int G = (gridDim.y * gridDim.z) >> 3;
    const int g = r8 * G + (kk8 % G);
    bx = kk8 / G; by = g % gridDim.y; bz = g / gridDim.y;
  } else {
    const int G = (gridDim.x * gridDim.z) >> 3;
    const int g = r8 * G + (kk8 % G);
    by = kk8 / G; bx = g % gridDim.x; bz = g / gridDim.x;
  }

  const int tid = threadIdx.x;
  const int lane = tid & 63, w = tid >> 6;
  const int quad = lane >> 4, lm = lane & 15;
  const int m0 = by << 7, n0 = bx << 7;
  A  += (size_t)bz * sA;
  Bt += (size_t)bz * sB;

  f32x4 acc[4][4];
  #pragma unroll
  for(int i=0;i<4;i++)
    #pragma unroll
    for(int j=0;j<4;j++) acc[i][j] = (f32x4){0.f,0.f,0.f,0.f};

  const int wm = (w & 1) << 6, wn = (w >> 1) << 6;
  const int srow = tid >> 3;
  const int sx   = (tid & 7) ^ (srow & 7);
  const uint16_t* ga = A  + (size_t)(m0 + srow)*lda + sx*8;
  const uint16_t* gb = Bt + (size_t)(n0 + srow)*ldb + sx*8;
  uint16_t* sa0 = &smem[tid*8];
  uint16_t* sb0 = &smem[8192 + tid*8];
  uint16_t* sa1 = &smem[16384 + tid*8];
  uint16_t* sb1 = &smem[24576 + tid*8];

  const int NT = K >> 6;
  #pragma unroll
  for(int i=0;i<4;i++){
    gload16(ga + (size_t)(i*32)*lda, sa0 + i*2048);
    gload16(gb + (size_t)(i*32)*ldb, sb0 + i*2048);
  }
  for(int t=0;t<NT;t++){
    if (t < NT-1){
      uint16_t* na = (t&1) ? sa0 : sa1;
      uint16_t* nb = (t&1) ? sb0 : sb1;
      const int k1 = (t+1)<<6;
      #pragma unroll
      for(int i=0;i<4;i++){
        gload16(ga + (size_t)(i*32)*lda + k1, na + i*2048);
        gload16(gb + (size_t)(i*32)*ldb + k1, nb + i*2048);
      }
      asm volatile("s_waitcnt vmcnt(8)" ::: "memory");
    } else {
      asm volatile("s_waitcnt vmcnt(0)" ::: "memory");
    }
    __builtin_amdgcn_s_barrier();
    __builtin_amdgcn_sched_barrier(0);
    const int boff = (t&1) << 14;
    #pragma unroll
    for(int kk=0;kk<64;kk+=32){
      bf16x8 av[4], bv[4];
      #pragma unroll
      for(int i=0;i<4;i++){
        const int row = wm + i*16 + lm;
        av[i] = *(const bf16x8*)&smem[boff + row*64 + ((((kk>>3)+quad) ^ (row&7))<<3)];
      }
      #pragma unroll
      for(int j=0;j<4;j++){
        const int row = wn + j*16 + lm;
        bv[j] = *(const bf16x8*)&smem[boff + 8192 + row*64 + ((((kk>>3)+quad) ^ (row&7))<<3)];
      }
      #pragma unroll
      for(int i=0;i<4;i++)
        #pragma unroll
        for(int j=0;j<4;j++)
          acc[i][j] = __builtin_amdgcn_mfma_f32_16x16x32_bf16(av[i], bv[j], acc[i][j], 0,0,0);
    }
    __builtin_amdgcn_s_barrier();
  }

  const size_t cb = (size_t)bz * (size_t)sC;
  if (!OUTDYN && !HASRES){
    uint16_t* Cs = smem;
    #pragma unroll
    for(int j=0;j<4;j++){
      const int col_l = wn + j*16 + lm;
      const float cbias = (HASBIAS && !BIASROW) ? bf2f(bias[n0 + col_l]) : 0.f;
      #pragma unroll
      for(int i=0;i<4;i++){
        const int rl0 = wm + i*16 + (quad<<2);
        #pragma unroll
        for(int r=0;r<4;r++){
          float v = acc[i][j][r] + cbias;
          if (HASBIAS && BIASROW) v += bf2f(bias[m0 + rl0 + r]);
          if (EXP) v = __expf(v * 0.044194173824159216f);
          Cs[(rl0+r)*128 + col_l] = f2bf(v);
        }
      }
    }
    __syncthreads();
    uint16_t* base = (uint16_t*)Cp + cb;
    #pragma unroll
    for(int k=0;k<8;k++){
      const int ci = tid + k*256;
      const int rl = ci>>4, cc = ci&15;
      *(uint4*)&base[(size_t)(m0+rl)*ldc + n0 + cc*8] = *(const uint4*)&Cs[rl*128 + cc*8];
    }
  } else {
    float* Cs32 = (float*)smem;
    const int f = OUTDYN ? *flag : 0;
    const int wnh = wn >> 1;
    #pragma unroll
    for(int half=0; half<2; ++half){
      #pragma unroll
      for(int j2=0;j2<2;j2++){
        const int j = half*2 + j2;
        const int col_l = wn + j*16 + lm;
        const int hcol = wnh + j2*16 + lm;
        const float cbias = (HASBIAS && !BIASROW) ? bf2f(bias[n0 + col_l]) : 0.f;
        #pragma unroll
        for(int i=0;i<4;i++){
          const int rl0 = wm + i*16 + (quad<<2);
          #pragma unroll
          for(int r=0;r<4;r++){
            float v = acc[i][j][r] + cbias;
            if (HASBIAS && BIASROW) v += bf2f(bias[m0 + rl0 + r]);
            if (EXP) v = __expf(v * 0.044194173824159216f);
            Cs32[(rl0+r)*64 + hcol] = v;
          }
        }
      }
      __syncthreads();
      #pragma unroll
      for(int k=0;k<8;k++){
        const int ci = tid + k*256;
        const int rl = ci>>4, c4 = ci&15;
        float4 vv = *(const float4*)&Cs32[rl*64 + c4*4];
        const int gcol = n0 + c4*4 + ((c4>=8)?32:0) + half*32;
        const size_t idx = cb + (size_t)(m0+rl)*ldc + gcol;
        float o0=vv.x, o1=vv.y, o2=vv.z, o3=vv.w;
        if (HASRES){
          uint2 rr = *(const uint2*)&xres[idx];
          o0 += bf2f((uint16_t)(rr.x & 0xffffu));
          o1 += bf2f((uint16_t)(rr.x >> 16));
          o2 += bf2f((uint16_t)(rr.y & 0xffffu));
          o3 += bf2f((uint16_t)(rr.y >> 16));
        }
        if (OUTDYN && f){
          float4 oo = make_float4(o0,o1,o2,o3);
          *(float4*)&((float*)Cp)[idx] = oo;
        } else {
          uint2 oo;
          oo.x = (uint32_t)f2bf(o0) | ((uint32_t)f2bf(o1)<<16);
          oo.y = (uint32_t)f2bf(o2) | ((uint32_t)f2bf(o3)<<16);
          *(uint2*)&((uint16_t*)Cp)[idx] = oo;
        }
      }
      __syncthreads();
    }
  }
}

extern "C" void kernel_launch(void* const* d_in, const int* in_sizes, int n_in,
                              void* d_out, int out_size, void* d_ws, size_t ws_size,
                              hipStream_t stream){
  char* ws = (char*)d_ws;
  int*      flag  = (int*)ws;
  float2*   part  = (float2*)(ws + 4096);
  uint16_t* gnwb  = (uint16_t*)(ws + 16384);
  uint16_t* gnbb  = (uint16_t*)(ws + 17408);
  uint16_t* qkvbb = (uint16_t*)(ws + 18432);
  uint16_t* projbb= (uint16_t*)(ws + 21504);
  uint16_t* qkvwb = (uint16_t*)(ws + 32768);          // 1.57 MB
  uint16_t* projwb= (uint16_t*)(ws + 1605632);        // 0.52 MB
  uint16_t* xb    = (uint16_t*)(ws + 4194304);        // 16.8 MB [B,C,S]
  uint16_t* hT    = (uint16_t*)(ws + 20971520);       // 16.8 MB [16384,512]; attn out
  uint16_t* qk    = (uint16_t*)(ws + 37748736);       // 33.6 MB [16384,1024] (Q|K)
  uint16_t* Vt    = (uint16_t*)(ws + 104857600);      // 16.8 MB [16,512,1024]

  static bool attr_done = false;
  if (!attr_done){
    (void)hipFuncSetAttribute(reinterpret_cast<const void*>(fa_k),
                              hipFuncAttributeMaxDynamicSharedMemorySize, 163840);
    attr_done = true;
  }

  hipLaunchKernelGGL(prep_k, dim3(1537), dim3(256), 0, stream,
                     d_in[0], xb, part,
                     d_in[3], d_in[5], d_in[1], d_in[2], d_in[4], d_in[6],
                     qkvwb, projwb, gnwb, gnbb, qkvbb, projbb, flag);
  hipLaunchKernelGGL(gn_apply_t, dim3(8,8,16), dim3(256), 0, stream, xb, gnwb, gnbb, part, hT);

  // merged QK + V^T
  hipLaunchKernelGGL(qkv_k, dim3(1536), dim3(256), 0, stream, hT, qkvwb, qkvbb, qk, Vt);

  // fused attention: softmax(QK^T*scale)·V -> hT[bs,512]
  hipLaunchKernelGGL(fa_k, dim3(256), dim3(1024), 163840, stream, qk, Vt, hT);

  // out[b,c,s] = projW · attn_b^T + projb + x
  hipLaunchKernelGGL((gemm_bt<true,true,true,true,1,false>), dim3(8,4,16), dim3(256), 0, stream,
      projwb, hT, d_out, projbb, xb, flag,
      512, 512, 1024, 512, 0LL, (long long)S_*C_, (long long)C_*S_);
}

// Round 8
// 203.708 us; speedup vs baseline: 1.6059x; 1.6059x over previous
//
#include <hip/hip_runtime.h>
#include <stdint.h>

#define B_  16
#define C_  512
#define S_  1024
#define NSAMP (C_*S_)

typedef __bf16 bf16x8 __attribute__((ext_vector_type(8)));
typedef float  f32x4  __attribute__((ext_vector_type(4)));

__device__ __forceinline__ float bf2f(uint16_t u){ return __uint_as_float(((uint32_t)u)<<16); }
__device__ __forceinline__ uint16_t f2bf(float f){
  uint32_t u = __float_as_uint(f);
  uint32_t r = u + 0x7fffu + ((u>>16)&1u);   // RNE
  return (uint16_t)(r>>16);
}
__device__ __forceinline__ float wsum(float v){
  #pragma unroll
  for(int o=32;o;o>>=1) v += __shfl_xor(v,o,64);
  return v;
}
__device__ __forceinline__ int wsumi(int v){
  #pragma unroll
  for(int o=32;o;o>>=1) v += __shfl_xor(v,o,64);
  return v;
}
__device__ __forceinline__ void gload16(const void* g, void* l){
  __builtin_amdgcn_global_load_lds(
      (__attribute__((address_space(1))) void*)g,
      (__attribute__((address_space(3))) void*)l, 16, 0, 0);
}

// ---------- merged prep: x->bf16 + GN partials (blocks 0..1023) | params->bf16 (1024..1536) ----------
__device__ __forceinline__ void convseg(const void* src, uint16_t* dst, int n, int f, int t){
  const int idx = t*8;
  if (idx >= n) return;
  if (f){
    const float* s = (const float*)src;
    float4 v0 = *(const float4*)(s + idx);
    float4 v1 = *(const float4*)(s + idx + 4);
    ushort4 a, b;
    a.x=f2bf(v0.x); a.y=f2bf(v0.y); a.z=f2bf(v0.z); a.w=f2bf(v0.w);
    b.x=f2bf(v1.x); b.y=f2bf(v1.y); b.z=f2bf(v1.z); b.w=f2bf(v1.w);
    *(ushort4*)(dst + idx)     = a;
    *(ushort4*)(dst + idx + 4) = b;
  } else {
    *(uint4*)(dst + idx) = *(const uint4*)((const uint16_t*)src + idx);
  }
}
__global__ __launch_bounds__(256) void prep_k(
    const void* __restrict__ srcx, uint16_t* __restrict__ xb, float2* __restrict__ part,
    const void* qkvw, const void* projw, const void* gnw, const void* gnb,
    const void* qkvb, const void* projb,
    uint16_t* qkvwb, uint16_t* projwb, uint16_t* gnwb, uint16_t* gnbb,
    uint16_t* qkvbb, uint16_t* projbb, int* __restrict__ flag){
  const int t = threadIdx.x;
  // ---- local dtype detect (all blocks, same 4KB of x, same answer) ----
  __shared__ int sdet[4];
  int f;
  {
    const uint4 v = ((const uint4*)srcx)[t & 255];
    uint32_t ww[4] = {v.x, v.y, v.z, v.w};
    int c = 0;
    #pragma unroll
    for(int q=0;q<4;q++) c += ((((ww[q] & 0xffffu) >> 7) & 0xffu) >= 132) ? 1 : 0;
    c = wsumi(c);
    if ((t & 63) == 0) sdet[t >> 6] = c;
    __syncthreads();
    f = (sdet[0] + sdet[1] + sdet[2] + sdet[3] > 128) ? 1 : 0;   // 1 => fp32
  }
  if (blockIdx.x == 0 && t == 0) *flag = f;   // for proj epilogue OUTDYN

  if (blockIdx.x >= 1024){
    const int bid = blockIdx.x - 1024;
    if (bid < 384){
      const size_t off = (size_t)bid*2048;
      convseg((const char*)qkvw + off*(f?4:2), qkvwb + off, 2048, f, t);
    } else if (bid < 512){
      const size_t off = (size_t)(bid-384)*2048;
      convseg((const char*)projw + off*(f?4:2), projwb + off, 2048, f, t);
    } else {
      convseg(gnw,   gnwb,   512,  f, t);
      convseg(gnb,   gnbb,   512,  f, t);
      convseg(qkvb,  qkvbb,  1536, f, t);
      convseg(projb, projbb, 512,  f, t);
    }
    return;
  }
  const size_t base = (size_t)blockIdx.x * 8192;
  float s = 0.f, s2 = 0.f;
  if (f){
    const float4* sp = (const float4*)((const float*)srcx + base);
    ushort4* dp = (ushort4*)(xb + base);
    #pragma unroll
    for(int i=0;i<8;i++){
      float4 v = sp[i*256 + t];
      s  += v.x + v.y + v.z + v.w;
      s2 += v.x*v.x + v.y*v.y + v.z*v.z + v.w*v.w;
      ushort4 o; o.x=f2bf(v.x); o.y=f2bf(v.y); o.z=f2bf(v.z); o.w=f2bf(v.w);
      dp[i*256 + t] = o;
    }
  } else {
    const uint4* sp = (const uint4*)((const uint16_t*)srcx + base);
    uint4* dp = (uint4*)(xb + base);
    #pragma unroll
    for(int i=0;i<4;i++){
      uint4 p = sp[i*256 + t];
      dp[i*256 + t] = p;
      uint32_t uu[4] = {p.x,p.y,p.z,p.w};
      #pragma unroll
      for(int q=0;q<4;q++){
        float f0 = __uint_as_float(uu[q]<<16);
        float f1 = __uint_as_float(uu[q] & 0xffff0000u);
        s += f0 + f1; s2 += f0*f0 + f1*f1;
      }
    }
  }
  s = wsum(s); s2 = wsum(s2);
  __shared__ float rs[4], rq[4];
  const int lane = t & 63, w = t >> 6;
  if (lane==0){ rs[w]=s; rq[w]=s2; }
  __syncthreads();
  if (t==0)
    part[blockIdx.x] = make_float2(rs[0]+rs[1]+rs[2]+rs[3], rq[0]+rq[1]+rq[2]+rq[3]);
}

// ---- GN apply + transpose [B,C,S] -> hT [B,S,C] bf16 ----
__global__ __launch_bounds__(256) void gn_apply_t(const uint16_t* __restrict__ x,
    const uint16_t* __restrict__ gw, const uint16_t* __restrict__ gb,
    const float2* __restrict__ part, uint16_t* __restrict__ hT){
  __shared__ float tile[64*129];          // 129-stride pad
  const int b = blockIdx.z, c0 = blockIdx.y<<6, s0 = blockIdx.x<<7;
  const int t = threadIdx.x;
  float2 p = part[b*64 + (t & 63)];
  float s = wsum(p.x), s2 = wsum(p.y);
  const float ninv = 1.f/(float)NSAMP;
  const float mn = s*ninv;
  const float rstd = rsqrtf(s2*ninv - mn*mn + 1e-5f);
  // load: 64 rows(c) x 128(s), 16B/lane
  #pragma unroll
  for(int k=0;k<4;k++){
    const int ci = t + k*256;
    const int cl = ci>>4, sc = ci&15;
    uint4 v = *(const uint4*)&x[((size_t)b*C_ + c0+cl)*S_ + s0 + sc*8];
    const uint16_t* e = (const uint16_t*)&v;
    float* dst = &tile[cl*129 + sc*8];
    #pragma unroll
    for(int q=0;q<8;q++) dst[q] = bf2f(e[q]);
  }
  __syncthreads();
  // store: 128 rows(s) x 64(c)
  const int cc = t & 7;
  const int sb0 = t >> 3;
  uint4 wv4 = *(const uint4*)&gw[c0 + cc*8];
  uint4 bv4 = *(const uint4*)&gb[c0 + cc*8];
  const uint16_t* we = (const uint16_t*)&wv4;
  const uint16_t* be = (const uint16_t*)&bv4;
  float aq[8], cq[8];
  #pragma unroll
  for(int q=0;q<8;q++){ aq[q] = bf2f(we[q])*rstd; cq[q] = bf2f(be[q]) - mn*aq[q]; }
  #pragma unroll
  for(int k=0;k<4;k++){
    const int sl = sb0 + k*32;
    uint16_t ov[8];
    #pragma unroll
    for(int q=0;q<8;q++){
      float xv = tile[(cc*8+q)*129 + sl];
      ov[q] = f2bf(xv*aq[q] + cq[q]);
    }
    uint4 o;
    o.x = (uint32_t)ov[0] | ((uint32_t)ov[1]<<16);
    o.y = (uint32_t)ov[2] | ((uint32_t)ov[3]<<16);
    o.z = (uint32_t)ov[4] | ((uint32_t)ov[5]<<16);
    o.w = (uint32_t)ov[6] | ((uint32_t)ov[7]<<16);
    *(uint4*)&hT[((size_t)b*S_ + s0+sl)*C_ + c0 + cc*8] = o;
  }
}

// ======== merged QK + V^T GEMMs (both read hT, K=512, lda=ldb=512) ========
// Double-buffered staging: stage t+1 into buf^1 BEFORE computing t; counted
// s_waitcnt vmcnt(8) leaves next-step loads in flight across the barrier.
__global__ __launch_bounds__(256)
void qkv_k(const uint16_t* __restrict__ hT, const uint16_t* __restrict__ qkvw,
           const uint16_t* __restrict__ qkvb, uint16_t* __restrict__ qk,
           uint16_t* __restrict__ Vt)
{
  __shared__ uint16_t smem[32768];       // 64KB: As0|Bs0|As1|Bs1; epilogue reuses 32KB
  const int tid = threadIdx.x;
  const int lane = tid & 63, w = tid >> 6;
  const int quad = lane >> 4, lm = lane & 15;
  const int wm = (w & 1) << 6, wn = (w >> 1) << 6;

  const bool vpath = blockIdx.x >= 1024;
  const int id = vpath ? (blockIdx.x - 1024) : blockIdx.x;
  const int r8 = id & 7, k8 = id >> 3;
  int m0, n0, bz;
  const uint16_t *Abase, *Bbase;
  if (!vpath){
    const int g = r8*16 + (k8 & 15);        // by 0..127
    m0 = g << 7; n0 = (k8 >> 4) << 7; bz = 0;
    Abase = hT + (size_t)m0*512;
    Bbase = qkvw + (size_t)n0*512;
  } else {
    const int g = r8*16 + (k8 & 15);        // 0..127 -> (bx,bz)
    m0 = (k8 >> 4) << 7; n0 = (g & 7) << 7; bz = g >> 3;
    Abase = qkvw + (size_t)(1024 + m0)*512;
    Bbase = hT + (size_t)bz*S_*C_ + (size_t)n0*512;
  }

  f32x4 acc[4][4];
  #pragma unroll
  for(int i=0;i<4;i++)
    #pragma unroll
    for(int j=0;j<4;j++) acc[i][j] = (f32x4){0.f,0.f,0.f,0.f};

  const int srow = tid >> 3;
  const int sx   = (tid & 7) ^ (srow & 7);
  const uint16_t* ga = Abase + (size_t)srow*512 + sx*8;
  const uint16_t* gb = Bbase + (size_t)srow*512 + sx*8;
  uint16_t* sa0 = &smem[tid*8];
  uint16_t* sb0 = &smem[8192 + tid*8];
  uint16_t* sa1 = &smem[16384 + tid*8];
  uint16_t* sb1 = &smem[24576 + tid*8];

  // prologue: stage k-step 0 into buf0
  #pragma unroll
  for(int i=0;i<4;i++){
    gload16(ga + (size_t)(i*32)*512, sa0 + i*2048);
    gload16(gb + (size_t)(i*32)*512, sb0 + i*2048);
  }
  for(int t=0;t<8;t++){
    if (t < 7){
      uint16_t* na = (t&1) ? sa0 : sa1;
      uint16_t* nb = (t&1) ? sb0 : sb1;
      const int k1 = (t+1)<<6;
      #pragma unroll
      for(int i=0;i<4;i++){
        gload16(ga + (size_t)(i*32)*512 + k1, na + i*2048);
        gload16(gb + (size_t)(i*32)*512 + k1, nb + i*2048);
      }
      asm volatile("s_waitcnt vmcnt(8)" ::: "memory");
    } else {
      asm volatile("s_waitcnt vmcnt(0)" ::: "memory");
    }
    __builtin_amdgcn_s_barrier();
    __builtin_amdgcn_sched_barrier(0);
    const int boff = (t&1) << 14;
    #pragma unroll
    for(int kk=0;kk<64;kk+=32){
      bf16x8 av[4], bv[4];
      #pragma unroll
      for(int i=0;i<4;i++){
        const int row = wm + i*16 + lm;
        av[i] = *(const bf16x8*)&smem[boff + row*64 + ((((kk>>3)+quad) ^ (row&7))<<3)];
      }
      #pragma unroll
      for(int j=0;j<4;j++){
        const int row = wn + j*16 + lm;
        bv[j] = *(const bf16x8*)&smem[boff + 8192 + row*64 + ((((kk>>3)+quad) ^ (row&7))<<3)];
      }
      #pragma unroll
      for(int i=0;i<4;i++)
        #pragma unroll
        for(int j=0;j<4;j++)
          acc[i][j] = __builtin_amdgcn_mfma_f32_16x16x32_bf16(av[i], bv[j], acc[i][j], 0,0,0);
    }
    __builtin_amdgcn_s_barrier();
  }

  // ---- epilogue: stage C-tile in LDS, write back coalesced uint4 ----
  uint16_t* Cs = smem;
  if (!vpath){
    #pragma unroll
    for(int j=0;j<4;j++){
      const int col_l = wn + j*16 + lm;
      const float bvv = bf2f(qkvb[n0 + col_l]);
      #pragma unroll
      for(int i=0;i<4;i++){
        const int rl0 = wm + i*16 + (quad<<2);
        #pragma unroll
        for(int r=0;r<4;r++)
          Cs[(rl0+r)*128 + col_l] = f2bf(acc[i][j][r] + bvv);
      }
    }
  } else {
    #pragma unroll
    for(int i=0;i<4;i++){
      const int rl0 = wm + i*16 + (quad<<2);
      #pragma unroll
      for(int r=0;r<4;r++){
        const float bvv = bf2f(qkvb[1024 + m0 + rl0 + r]);
        #pragma unroll
        for(int j=0;j<4;j++)
          Cs[(rl0+r)*128 + wn + j*16 + lm] = f2bf(acc[i][j][r] + bvv);
      }
    }
  }
  __syncthreads();
  uint16_t* base = vpath ? (Vt + (size_t)bz*C_*S_) : qk;
  #pragma unroll
  for(int k=0;k<8;k++){
    const int ci = tid + k*256;
    const int rl = ci>>4, ccc = ci&15;
    *(uint4*)&base[(size_t)(m0+rl)*1024 + n0 + ccc*8] = *(const uint4*)&Cs[rl*128 + ccc*8];
  }
}

// ---------------- 128x128 MFMA GEMM, C = A * Bt^T (double-buffered) ----------------
// RSMODE: 0 none; 1 = write per-block row partial sums of epilogue values (scores);
//         2 = divide by sum of the 16 partials per row (PV).
template<bool HASBIAS, bool BIASROW, bool OUTDYN, bool HASRES, int SWZMODE, bool EXP, int RSMODE>
__global__ __launch_bounds__(256)
void gemm_bt(const uint16_t* __restrict__ A, const uint16_t* __restrict__ Bt,
             void* __restrict__ Cp, const uint16_t* __restrict__ bias,
             const uint16_t* __restrict__ xres, const int* __restrict__ flag,
             float* __restrict__ rs_part,
             int lda, int ldb, int ldc, int K,
             long long sA, long long sB, long long sC)
{
  __shared__ uint16_t smem[32768];       // 64KB: As0|Bs0|As1|Bs1; epilogue reuses 32KB
  const int lin = (blockIdx.z * gridDim.y + blockIdx.y) * gridDim.x + blockIdx.x;
  const int r8 = lin & 7, kk8 = lin >> 3;
  int bx, by, bz;
  if (SWZMODE == 0){
    const int G = (gridDim.y * gridDim.z) >> 3;
    const int g = r8 * G + (kk8 % G);
    bx = kk8 / G; by = g % gridDim.y; bz = g / gridDim.y;
  } else {
    const int G = (gridDim.x * gridDim.z) >> 3;
    const int g = r8 * G + (kk8 % G);
    by = kk8 / G; bx = g % gridDim.x; bz = g / gridDim.x;
  }

  const int tid = threadIdx.x;
  const int lane = tid & 63, w = tid >> 6;
  const int quad = lane >> 4, lm = lane & 15;
  const int m0 = by << 7, n0 = bx << 7;
  A  += (size_t)bz * sA;
  Bt += (size_t)bz * sB;

  f32x4 acc[4][4];
  #pragma unroll
  for(int i=0;i<4;i++)
    #pragma unroll
    for(int j=0;j<4;j++) acc[i][j] = (f32x4){0.f,0.f,0.f,0.f};

  const int wm = (w & 1) << 6, wn = (w >> 1) << 6;
  const int srow = tid >> 3;
  const int sx   = (tid & 7) ^ (srow & 7);
  const uint16_t* ga = A  + (size_t)(m0 + srow)*lda + sx*8;
  const uint16_t* gb = Bt + (size_t)(n0 + srow)*ldb + sx*8;
  uint16_t* sa0 = &smem[tid*8];
  uint16_t* sb0 = &smem[8192 + tid*8];
  uint16_t* sa1 = &smem[16384 + tid*8];
  uint16_t* sb1 = &smem[24576 + tid*8];

  const int NT = K >> 6;
  // prologue: stage k-step 0 into buf0
  #pragma unroll
  for(int i=0;i<4;i++){
    gload16(ga + (size_t)(i*32)*lda, sa0 + i*2048);
    gload16(gb + (size_t)(i*32)*ldb, sb0 + i*2048);
  }
  for(int t=0;t<NT;t++){
    if (t < NT-1){
      uint16_t* na = (t&1) ? sa0 : sa1;
      uint16_t* nb = (t&1) ? sb0 : sb1;
      const int k1 = (t+1)<<6;
      #pragma unroll
      for(int i=0;i<4;i++){
        gload16(ga + (size_t)(i*32)*lda + k1, na + i*2048);
        gload16(gb + (size_t)(i*32)*ldb + k1, nb + i*2048);
      }
      asm volatile("s_waitcnt vmcnt(8)" ::: "memory");
    } else {
      asm volatile("s_waitcnt vmcnt(0)" ::: "memory");
    }
    __builtin_amdgcn_s_barrier();
    __builtin_amdgcn_sched_barrier(0);
    const int boff = (t&1) << 14;
    #pragma unroll
    for(int kk=0;kk<64;kk+=32){
      bf16x8 av[4], bv[4];
      #pragma unroll
      for(int i=0;i<4;i++){
        const int row = wm + i*16 + lm;
        av[i] = *(const bf16x8*)&smem[boff + row*64 + ((((kk>>3)+quad) ^ (row&7))<<3)];
      }
      #pragma unroll
      for(int j=0;j<4;j++){
        const int row = wn + j*16 + lm;
        bv[j] = *(const bf16x8*)&smem[boff + 8192 + row*64 + ((((kk>>3)+quad) ^ (row&7))<<3)];
      }
      #pragma unroll
      for(int i=0;i<4;i++)
        #pragma unroll
        for(int j=0;j<4;j++)
          acc[i][j] = __builtin_amdgcn_mfma_f32_16x16x32_bf16(av[i], bv[j], acc[i][j], 0,0,0);
    }
    __builtin_amdgcn_s_barrier();
  }

  const size_t cb = (size_t)bz * (size_t)sC;
  if (!OUTDYN && !HASRES){
    // bf16 output: stage rounded bf16 tile, write coalesced
    uint16_t* Cs = smem;
    float rp[4][4];
    if (RSMODE == 1){
      #pragma unroll
      for(int i=0;i<4;i++)
        #pragma unroll
        for(int r=0;r<4;r++) rp[i][r] = 0.f;
    }
    float inv[4][4];
    if (RSMODE == 2){
      // lane (quad, lm) owns in-wave row lm*4+quad; load its 16 partials, sum
      const int myrow = m0 + wm + lm*4 + quad;
      const float4* rpp = (const float4*)&rs_part[((size_t)bz*1024 + myrow)*16];
      float4 a0 = rpp[0], a1 = rpp[1], a2 = rpp[2], a3 = rpp[3];
      float rowsumv = a0.x+a0.y+a0.z+a0.w + a1.x+a1.y+a1.z+a1.w
                    + a2.x+a2.y+a2.z+a2.w + a3.x+a3.y+a3.z+a3.w;
      #pragma unroll
      for(int i=0;i<4;i++)
        #pragma unroll
        for(int r=0;r<4;r++)
          inv[i][r] = 1.f / __shfl(rowsumv, r*16 + i*4 + quad, 64);
    }
    #pragma unroll
    for(int j=0;j<4;j++){
      const int col_l = wn + j*16 + lm;
      const float cbias = (HASBIAS && !BIASROW) ? bf2f(bias[n0 + col_l]) : 0.f;
      #pragma unroll
      for(int i=0;i<4;i++){
        const int rl0 = wm + i*16 + (quad<<2);
        #pragma unroll
        for(int r=0;r<4;r++){
          float v = acc[i][j][r] + cbias;
          if (HASBIAS && BIASROW) v += bf2f(bias[m0 + rl0 + r]);
          if (EXP)          v = __expf(v * 0.044194173824159216f);   // 512^-0.5
          if (RSMODE == 1)  rp[i][r] += v;
          if (RSMODE == 2)  v *= inv[i][r];
          Cs[(rl0+r)*128 + col_l] = f2bf(v);
        }
      }
    }
    if (RSMODE == 1){
      // reduce over the 16 lanes of the quad group; lane lm==0 stores partial
      #pragma unroll
      for(int i=0;i<4;i++)
        #pragma unroll
        for(int r=0;r<4;r++){
          float s4 = rp[i][r];
          #pragma unroll
          for(int o=8;o;o>>=1) s4 += __shfl_xor(s4, o, 64);
          if (lm == 0)
            rs_part[((size_t)bz*1024 + m0 + wm + i*16 + (quad<<2) + r)*16 + (bx<<1) + (w>>1)] = s4;
        }
    }
    __syncthreads();
    uint16_t* base = (uint16_t*)Cp + cb;
    #pragma unroll
    for(int k=0;k<8;k++){
      const int ci = tid + k*256;
      const int rl = ci>>4, cc = ci&15;
      *(uint4*)&base[(size_t)(m0+rl)*ldc + n0 + cc*8] = *(const uint4*)&Cs[rl*128 + cc*8];
    }
  } else {
    // f32 staging in two 128x64 half-tiles; vectorized residual read + dyn-dtype store
    float* Cs32 = (float*)smem;
    const int f = OUTDYN ? *flag : 0;
    const int wnh = wn >> 1;
    #pragma unroll
    for(int half=0; half<2; ++half){
      #pragma unroll
      for(int j2=0;j2<2;j2++){
        const int j = half*2 + j2;
        const int col_l = wn + j*16 + lm;
        const int hcol = wnh + j2*16 + lm;
        const float cbias = (HASBIAS && !BIASROW) ? bf2f(bias[n0 + col_l]) : 0.f;
        #pragma unroll
        for(int i=0;i<4;i++){
          const int rl0 = wm + i*16 + (quad<<2);
          #pragma unroll
          for(int r=0;r<4;r++){
            float v = acc[i][j][r] + cbias;
            if (HASBIAS && BIASROW) v += bf2f(bias[m0 + rl0 + r]);
            if (EXP) v = __expf(v * 0.044194173824159216f);
            Cs32[(rl0+r)*64 + hcol] = v;
          }
        }
      }
      __syncthreads();
      #pragma unroll
      for(int k=0;k<8;k++){
        const int ci = tid + k*256;
        const int rl = ci>>4, c4 = ci&15;
        float4 vv = *(const float4*)&Cs32[rl*64 + c4*4];
        const int gcol = n0 + c4*4 + ((c4>=8)?32:0) + half*32;
        const size_t idx = cb + (size_t)(m0+rl)*ldc + gcol;
        float o0=vv.x, o1=vv.y, o2=vv.z, o3=vv.w;
        if (HASRES){
          uint2 rr = *(const uint2*)&xres[idx];
          o0 += bf2f((uint16_t)(rr.x & 0xffffu));
          o1 += bf2f((uint16_t)(rr.x >> 16));
          o2 += bf2f((uint16_t)(rr.y & 0xffffu));
          o3 += bf2f((uint16_t)(rr.y >> 16));
        }
        if (OUTDYN && f){
          float4 o = make_float4(o0,o1,o2,o3);
          *(float4*)&((float*)Cp)[idx] = o;
        } else {
          uint2 o;
          o.x = (uint32_t)f2bf(o0) | ((uint32_t)f2bf(o1)<<16);
          o.y = (uint32_t)f2bf(o2) | ((uint32_t)f2bf(o3)<<16);
          *(uint2*)&((uint16_t*)Cp)[idx] = o;
        }
      }
      __syncthreads();
    }
  }
}

extern "C" void kernel_launch(void* const* d_in, const int* in_sizes, int n_in,
                              void* d_out, int out_size, void* d_ws, size_t ws_size,
                              hipStream_t stream){
  char* ws = (char*)d_ws;
  int*      flag  = (int*)ws;
  float2*   part  = (float2*)(ws + 4096);
  uint16_t* gnwb  = (uint16_t*)(ws + 16384);
  uint16_t* gnbb  = (uint16_t*)(ws + 17408);
  uint16_t* qkvbb = (uint16_t*)(ws + 18432);
  uint16_t* projbb= (uint16_t*)(ws + 21504);
  uint16_t* qkvwb = (uint16_t*)(ws + 32768);          // 1.57 MB
  uint16_t* projwb= (uint16_t*)(ws + 1605632);        // 0.52 MB, ends 2129920
  float*    rs_part=(float*)  (ws + 2129920);         // 1.0 MB [16384][16], ends 3178496
  uint16_t* xb    = (uint16_t*)(ws + 4194304);        // 16.8 MB [B,C,S]
  uint16_t* hT    = (uint16_t*)(ws + 20971520);       // 16.8 MB [16384,512]; reused for attn
  uint16_t* qk    = (uint16_t*)(ws + 37748736);       // 33.6 MB [16384,1024] (Q|K)
  uint16_t* sc    = (uint16_t*)(ws + 71303168);       // 33.6 MB [16,1024,1024] P'
  uint16_t* Vt    = (uint16_t*)(ws + 104857600);      // 16.8 MB [16,512,1024]
  // end ~121.6 MB

  hipLaunchKernelGGL(prep_k, dim3(1537), dim3(256), 0, stream,
                     d_in[0], xb, part,
                     d_in[3], d_in[5], d_in[1], d_in[2], d_in[4], d_in[6],
                     qkvwb, projwb, gnwb, gnbb, qkvbb, projbb, flag);
  hipLaunchKernelGGL(gn_apply_t, dim3(8,8,16), dim3(256), 0, stream, xb, gnwb, gnbb, part, hT);

  // merged QK + V^T
  hipLaunchKernelGGL(qkv_k, dim3(1536), dim3(256), 0, stream, hT, qkvwb, qkvbb, qk, Vt);

  // P' = exp(scale * Q K^T) (bf16) + per-block row partial sums
  hipLaunchKernelGGL((gemm_bt<false,false,false,false,0,true,1>), dim3(8,8,16), dim3(256), 0, stream,
      qk, qk + 512, (void*)sc, (const uint16_t*)nullptr, (const uint16_t*)nullptr, flag, rs_part,
      1024, 1024, 1024, 512, (long long)S_*1024, (long long)S_*1024, (long long)S_*S_);

  // attn = (P' V) / rowsum: per batch [1024,1024] x [512,1024]^T -> hT[bs,512]
  hipLaunchKernelGGL((gemm_bt<false,false,false,false,0,false,2>), dim3(4,8,16), dim3(256), 0, stream,
      sc, Vt, (void*)hT, (const uint16_t*)nullptr, (const uint16_t*)nullptr, flag, rs_part,
      1024, 1024, 512, 1024, (long long)S_*S_, (long long)C_*S_, (long long)S_*C_);

  // out[b,c,s] = projW · attn_b^T + projb + x
  hipLaunchKernelGGL((gemm_bt<true,true,true,true,1,false,0>), dim3(8,4,16), dim3(256), 0, stream,
      projwb, hT, d_out, projbb, xb, flag, (float*)nullptr,
      512, 512, 1024, 512, 0LL, (long long)S_*C_, (long long)C_*S_);
}